// Round 21
// baseline (54.843 us; speedup 1.0000x reference)
//
#include <hip/hip_runtime.h>
#include <math.h>

#define Bq 64
#define Tq 1024
#define Nq 128
#define SEG 65               // segments per chain (R18-R20-proven)
#define NFW (SEG - 1)
#define NBW (SEG - 1)
#define WPC 8                // worker waves per chain (4 fwd + 4 bwd)
#define LN2 0.6931471805599453f

typedef __attribute__((ext_vector_type(8))) _Float16 half8;
typedef __attribute__((ext_vector_type(2))) _Float16 h2;
typedef __attribute__((ext_vector_type(4))) float f32x4;

union BU { int u[4]; int4 v; half8 h; };
union E8 { int2 v; h2 p[2]; };          // 4 f16
union E16 { int2 v2[2]; half8 h; };     // 8 f16 as two int2 loads

__device__ __forceinline__ int pk16(float a, float b) {
    auto p = __builtin_amdgcn_cvt_pkrtz(a, b);
    return *(int*)&p;
}

// Permuted m-slot map (R20-proven): k-slot (call q, lane-group g, word j) holds
//   m = 16*(2q + (j>>2)) + 4g + (j&3)  == D-slot (same lane, acc[2q+(j>>2)], reg j&3)
__device__ __forceinline__ int MMAP(int q, int g, int j) {
    return 16 * (2 * q + (j >> 2)) + 4 * g + (j & 3);
}

// ---------------------------------------------------------------------------
// Tiny prep: pack exp(transitions) into PERMUTED fragment layout (16 blocks).
// ---------------------------------------------------------------------------
__global__ __launch_bounds__(256)
void crf_prep_kernel(const float* __restrict__ trans,
                     int4* __restrict__ aF, int4* __restrict__ aB) {
    const int fb = blockIdx.x;            // 0..7 aF, 8..15 aB
    const bool fwd = (fb < 8);
    const int kf = (fb & 7) * 4 + (threadIdx.x >> 6);   // fragment 0..31
    const int L = threadIdx.x & 63;
    const int c = L & 15, g = L >> 4;
    const int r = kf >> 2, q = kf & 3;
    BU v;
    #pragma unroll
    for (int j = 0; j < 8; ++j) {
        const int m = MMAP(q, g, j);
        const int n = 16 * r + c;
        const float tv = fwd ? trans[m * Nq + n] : trans[n * Nq + m];
        v.h[j] = (_Float16)__expf(tv);
    }
    (fwd ? aF : aB)[kf * 64 + L] = v.v;
}

// ---------------------------------------------------------------------------
// FWD step — R20 body; ee prefetch now from LDS (slot = min(k, lenc-1)).
// ---------------------------------------------------------------------------
__device__ __forceinline__ void fwd_step(
    int k, int lenc, int g,
    const _Float16 (&eeL)[16][Nq],
    const half8 (&afrag)[32], BU (&bf)[4],
    E8 (&eeCur)[8], E8 (&eeNxt)[8], int& Ecum)
{
    f32x4 acc[8];
    #pragma unroll
    for (int r = 0; r < 8; ++r) {
        f32x4 z = {0.f, 0.f, 0.f, 0.f};
        z = __builtin_amdgcn_mfma_f32_16x16x32_f16(afrag[r*4+0], bf[0].h, z, 0, 0, 0);
        z = __builtin_amdgcn_mfma_f32_16x16x32_f16(afrag[r*4+1], bf[1].h, z, 0, 0, 0);
        z = __builtin_amdgcn_mfma_f32_16x16x32_f16(afrag[r*4+2], bf[2].h, z, 0, 0, 0);
        z = __builtin_amdgcn_mfma_f32_16x16x32_f16(afrag[r*4+3], bf[3].h, z, 0, 0, 0);
        acc[r] = z;
    }
    {   // prefetch next step's ee from LDS (D layout: 8 x 8B, g-broadcast)
        const int sl = min(k, lenc - 1);
        const _Float16* bp = &eeL[sl][0];
        #pragma unroll
        for (int r = 0; r < 8; ++r)
            eeNxt[r].v = *(const int2*)(bp + 16*r + 4*g);
    }
    float w[32];
    float mx = 0.f;
    #pragma unroll
    for (int r = 0; r < 8; ++r) {
        #pragma unroll
        for (int i = 0; i < 4; ++i) {
            const float ee = (float)eeCur[r].p[i >> 1][i & 1];
            const float wv = acc[r][i] * ee;
            w[r*4+i] = wv;
            mx = fmaxf(mx, wv);
        }
    }
    mx = fmaxf(mx, __shfl_xor(mx, 16, 64));
    mx = fmaxf(mx, __shfl_xor(mx, 32, 64));
    const int eb = (__float_as_int(mx) >> 23) & 255;
    const float sig = __int_as_float((253 - eb) << 23);
    const bool act = (k <= lenc);
    #pragma unroll
    for (int q = 0; q < 4; ++q) {   // D -> B: lane-local (permuted-E layout)
        const int n0 = pk16(w[8*q+0]*sig, w[8*q+1]*sig);
        const int n1 = pk16(w[8*q+2]*sig, w[8*q+3]*sig);
        const int n2 = pk16(w[8*q+4]*sig, w[8*q+5]*sig);
        const int n3 = pk16(w[8*q+6]*sig, w[8*q+7]*sig);
        bf[q].u[0] = act ? n0 : bf[q].u[0];
        bf[q].u[1] = act ? n1 : bf[q].u[1];
        bf[q].u[2] = act ? n2 : bf[q].u[2];
        bf[q].u[3] = act ? n3 : bf[q].u[3];
    }
    Ecum += act ? (eb - 126) : 0;
}

// ---------------------------------------------------------------------------
// BWD step — R20 body; ee prefetch now from LDS.
// ---------------------------------------------------------------------------
__device__ __forceinline__ void bwd_step(
    int k, int lenc, int g,
    const _Float16 (&eeL)[16][Nq],
    const half8 (&afrag)[32], BU (&bf)[4],
    E16 (&eeCur)[4], E16 (&eeNxt)[4], int& Ecum)
{
    BU beff[4];
    #pragma unroll
    for (int q = 0; q < 4; ++q) beff[q].h = bf[q].h * eeCur[q].h;  // v_pk_mul_f16
    f32x4 acc[8];
    #pragma unroll
    for (int r = 0; r < 8; ++r) {
        f32x4 z = {0.f, 0.f, 0.f, 0.f};
        z = __builtin_amdgcn_mfma_f32_16x16x32_f16(afrag[r*4+0], beff[0].h, z, 0, 0, 0);
        z = __builtin_amdgcn_mfma_f32_16x16x32_f16(afrag[r*4+1], beff[1].h, z, 0, 0, 0);
        z = __builtin_amdgcn_mfma_f32_16x16x32_f16(afrag[r*4+2], beff[2].h, z, 0, 0, 0);
        z = __builtin_amdgcn_mfma_f32_16x16x32_f16(afrag[r*4+3], beff[3].h, z, 0, 0, 0);
        acc[r] = z;
    }
    {   // prefetch next step's ee from LDS (permuted B layout: 2 int2 per q)
        const int sl = min(k, lenc - 1);
        const _Float16* bp = &eeL[sl][0];
        #pragma unroll
        for (int q = 0; q < 4; ++q) {
            eeNxt[q].v2[0] = *(const int2*)(bp + 32*q + 4*g);
            eeNxt[q].v2[1] = *(const int2*)(bp + 32*q + 16 + 4*g);
        }
    }
    float mx = 0.f;
    #pragma unroll
    for (int r = 0; r < 8; ++r) {
        #pragma unroll
        for (int i = 0; i < 4; ++i) mx = fmaxf(mx, acc[r][i]);
    }
    mx = fmaxf(mx, __shfl_xor(mx, 16, 64));
    mx = fmaxf(mx, __shfl_xor(mx, 32, 64));
    const int eb = (__float_as_int(mx) >> 23) & 255;
    const float sig = __int_as_float((253 - eb) << 23);
    const bool act = (k <= lenc);
    #pragma unroll
    for (int q = 0; q < 4; ++q) {
        const int n0 = pk16(acc[2*q][0]*sig,   acc[2*q][1]*sig);
        const int n1 = pk16(acc[2*q][2]*sig,   acc[2*q][3]*sig);
        const int n2 = pk16(acc[2*q+1][0]*sig, acc[2*q+1][1]*sig);
        const int n3 = pk16(acc[2*q+1][2]*sig, acc[2*q+1][3]*sig);
        bf[q].u[0] = act ? n0 : bf[q].u[0];
        bf[q].u[1] = act ? n1 : bf[q].u[1];
        bf[q].u[2] = act ? n2 : bf[q].u[2];
        bf[q].u[3] = act ? n3 : bf[q].u[3];
    }
    Ecum += act ? (eb - 126) : 0;
}

// ---------------------------------------------------------------------------
// Blocks 0..511: worker waves. bid: chain b=bid>>3, wv=bid&7 (0..3 fwd, 4..7 bwd).
// Blocks 512..767: score partials (4 per chain).
// ---------------------------------------------------------------------------
__global__ __launch_bounds__(64, 1)
void crf_worker_kernel(const float* __restrict__ emissions,
                       const int4* __restrict__ aF,
                       const int4* __restrict__ aB,
                       const int* __restrict__ token_sizes,
                       const int* __restrict__ targets,
                       const float* __restrict__ transitions,
                       const float* __restrict__ head,
                       const float* __restrict__ last,
                       float* __restrict__ wsA, float* __restrict__ wsB,
                       float* __restrict__ wsLa, float* __restrict__ wsLb,
                       float* __restrict__ wsS) {
    const int L = threadIdx.x;
    const int bid = blockIdx.x;

    __shared__ __align__(16) _Float16 eeL[16][Nq];   // segment ee stage (4 KB)

    if (bid >= Bq * WPC) {
        // ---------------- score partials ----------------
        const int sb = bid - Bq * WPC;
        const int b = sb >> 2;
        const int j = sb & 3;
        const int tsz = token_sizes[b];
        const int* tg = targets + b * Tq;
        const float* em = emissions + (size_t)b * Tq * Nq;
        float sc = 0.f;
        for (int t = 64 * j + L; t < tsz; t += 256) {
            int cur = tg[t];
            sc += em[(size_t)t * Nq + cur];
            if (t >= 1) sc += transitions[tg[t - 1] * Nq + cur];
        }
        #pragma unroll
        for (int off = 32; off >= 1; off >>= 1)
            sc += __shfl_xor(sc, off, 64);
        if (L == 0) {
            const float extra = (j == 0) ? (head[tg[0]] + last[tg[tsz - 1]]) : 0.f;
            wsS[j * Bq + b] = sc + extra;
        }
        return;
    }

    const int b = bid >> 3;
    const int wv = bid & 7;
    const bool isFwd = (wv < 4);
    const int half_ = wv & 3;
    const int c = L & 15;
    const int g = L >> 4;
    const int s = (isFwd ? 1 : 2) + 16 * half_ + c;

    const float* em_c = emissions + (size_t)b * Tq * Nq;
    const int tsz = token_sizes[b];
    const int nst = tsz - 1;
    const int base = nst / SEG;
    const int rem = nst % SEG;
    const int lo = 1 + (s - 1) * base + min(s - 1, rem);
    const int lenc = base + ((s <= rem) ? 1 : 0);
    const int hi = lo + lenc - 1;
    const int kmax = base + 1;

    // lo/hi differ per lane (s depends on c) — but LDS staging must be
    // wave-uniform. It is NOT: each lane's column owns a different segment!
    // Stage per-lane-GROUP is impossible; instead each LANE stages its own
    // column's rows?? -> No: the wave shares eeL across columns. Resolve by
    // staging with per-lane addressing: lane L stages the rows of the
    // segment of column (L&15)?? Columns differ. The correct fix: the ee
    // rows CONSUMED by lane (c,g) in step k are from column c's segment
    // (row lo(c)+k-1). Stage slot i, column c's row into eeL[i][col-block]:
    // each lane loads 2 f32 from ITS OWN column's row; D/B-layout reads in
    // the loop then pick lane-appropriate values. Stage below does exactly
    // this: lane (c,g) writes eeL[i][<the 2 elements it will read>]... but
    // loop reads are g-broadcast (16 lanes share an address) -> those 16
    // lanes have DIFFERENT segments (c varies). CONTRADICTION.
    //
    // => Per-wave segments must be COLUMN-UNIFORM for LDS staging. They are
    // not in this decomposition, so we stage per-lane consumed values
    // directly in the exact (slot, lane, position) order each lane reads:
    // eeL is indexed [slot][lane-private 16 f16]: lane L uses
    // eeL[slot][...] region L*... -- reorganize as eeLP[16][64][2] int:
    // FWD lane needs 8x int2 per slot = 16 f16; BWD needs 16 f16 too.
    // LDS = 16 slots * 64 lanes * 16 f16 * 2B = 32 KB. Too big? 32 KB is
    // fine (1 block/CU target, but we want 2-3...). Occupancy: 160KB/32KB
    // = 5 blocks/CU -> OK.

    const int kmaxS = 16;    // stage all 16 slots
    // Per-lane staging: for slot i, this lane's consumed 16 f16 values are
    // emission elements of ITS column's row r_i at D-layout (FWD) or
    // B-layout (BWD) positions.
    {
        float* myrow = nullptr;  // silence unused warnings
        (void)myrow;
        #pragma unroll
        for (int i = 0; i < kmaxS; ++i) {
            const int row = isFwd ? min(lo + i, hi) : max(hi - i, lo);
            const float* bp = em_c + (size_t)row * Nq;
            int* dst = (int*)&eeL[i][0];     // viewed as [64 lanes][8 ints]... see layout below
            if (isFwd) {
                // D layout: positions 16r+4g .. +1, r=0..7  (8 int2 halves -> 8 ints of 2 f16)
                #pragma unroll
                for (int r = 0; r < 8; ++r) {
                    const float2 x = *(const float2*)(bp + 16*r + 4*g + ((L & 1) ? 2 : 0));
                    // lanes within a 16-group read SAME base; stagger by L&1 to
                    // cover 4 f16 per (r,g): lane even covers [0,1], odd [2,3]
                    dst[(L & 31) * 0 + 0] = 0; // placeholder — replaced below
                    (void)x;
                }
            }
            break; // fallthrough to simple path below
        }
    }

    // --- The clean, correct staging: since g-broadcast lanes share c?? No.
    // SIMPLEST CORRECT PATH (used here): bypass LDS for ee and load directly
    // from global raw f32 emissions with per-lane addresses + local exp/pack,
    // exactly matching each lane's consumption pattern. This keeps bits
    // identical (pk16(expf,expf)) and needs no staging at all. The prefetch
    // depth-1 double buffer hides L3 latency as in R17/R18 (which passed).

    half8 afrag[32];
    {
        const int4* asrc = isFwd ? aF : aB;
        #pragma unroll
        for (int kf = 0; kf < 32; ++kf) {
            BU t; t.v = asrc[kf * 64 + L];
            afrag[kf] = t.h;
        }
    }

    BU bf[4];
    float M0c;
    {
        float a0[32];
        float mx = -1e30f;
        #pragma unroll
        for (int q = 0; q < 4; ++q) {
            #pragma unroll
            for (int j2 = 0; j2 < 8; ++j2) {
                const int m = MMAP(q, g, j2);
                float v;
                if (isFwd) v = (s == 1)   ? (head[m] + em_c[m]) : 0.f;
                else       v = (s == SEG) ? last[m]             : 0.f;
                a0[q*8+j2] = v;
                mx = fmaxf(mx, v);
            }
        }
        mx = fmaxf(mx, __shfl_xor(mx, 16, 64));
        mx = fmaxf(mx, __shfl_xor(mx, 32, 64));
        M0c = mx;
        #pragma unroll
        for (int q = 0; q < 4; ++q) {
            #pragma unroll
            for (int p = 0; p < 4; ++p)
                bf[q].u[p] = pk16(__expf(a0[q*8+2*p]   - M0c),
                                  __expf(a0[q*8+2*p+1] - M0c));
        }
    }

    int Ecum = 0;
    int k = 1;
    if (isFwd) {
        // ee pipeline: raw f32 loads (float2 per r), exp+pack off critical path
        E8 eeA[8], eeB8[8];
        {
            const float* bp = em_c + (size_t)lo * Nq;
            #pragma unroll
            for (int r = 0; r < 8; ++r) {
                const float2 x = *(const float2*)(bp + 16*r + 4*g + 2*(0));
                const float2 y = *(const float2*)(bp + 16*r + 4*g + 2);
                eeA[r].v = make_int2(pk16(__expf(x.x), __expf(x.y)),
                                     pk16(__expf(y.x), __expf(y.y)));
            }
        }
        for (; k + 1 <= kmax; k += 2) {
            // inline fwd_step with raw-global prefetch
            {
                f32x4 acc[8];
                #pragma unroll
                for (int r = 0; r < 8; ++r) {
                    f32x4 z = {0.f, 0.f, 0.f, 0.f};
                    z = __builtin_amdgcn_mfma_f32_16x16x32_f16(afrag[r*4+0], bf[0].h, z, 0, 0, 0);
                    z = __builtin_amdgcn_mfma_f32_16x16x32_f16(afrag[r*4+1], bf[1].h, z, 0, 0, 0);
                    z = __builtin_amdgcn_mfma_f32_16x16x32_f16(afrag[r*4+2], bf[2].h, z, 0, 0, 0);
                    z = __builtin_amdgcn_mfma_f32_16x16x32_f16(afrag[r*4+3], bf[3].h, z, 0, 0, 0);
                    acc[r] = z;
                }
                const int tn = min(lo + k, hi);
                const float* bp = em_c + (size_t)tn * Nq;
                #pragma unroll
                for (int r = 0; r < 8; ++r) {
                    const float2 x = *(const float2*)(bp + 16*r + 4*g);
                    const float2 y = *(const float2*)(bp + 16*r + 4*g + 2);
                    eeB8[r].v = make_int2(pk16(__expf(x.x), __expf(x.y)),
                                          pk16(__expf(y.x), __expf(y.y)));
                }
                float w[32]; float mx = 0.f;
                #pragma unroll
                for (int r = 0; r < 8; ++r)
                    #pragma unroll
                    for (int i = 0; i < 4; ++i) {
                        const float ee = (float)eeA[r].p[i >> 1][i & 1];
                        const float wv2 = acc[r][i] * ee;
                        w[r*4+i] = wv2; mx = fmaxf(mx, wv2);
                    }
                mx = fmaxf(mx, __shfl_xor(mx, 16, 64));
                mx = fmaxf(mx, __shfl_xor(mx, 32, 64));
                const int eb = (__float_as_int(mx) >> 23) & 255;
                const float sig = __int_as_float((253 - eb) << 23);
                const bool act = (k <= lenc);
                #pragma unroll
                for (int q = 0; q < 4; ++q) {
                    const int n0 = pk16(w[8*q+0]*sig, w[8*q+1]*sig);
                    const int n1 = pk16(w[8*q+2]*sig, w[8*q+3]*sig);
                    const int n2 = pk16(w[8*q+4]*sig, w[8*q+5]*sig);
                    const int n3 = pk16(w[8*q+6]*sig, w[8*q+7]*sig);
                    bf[0+q].u[0] = act ? n0 : bf[q].u[0];
                    bf[q].u[1] = act ? n1 : bf[q].u[1];
                    bf[q].u[2] = act ? n2 : bf[q].u[2];
                    bf[q].u[3] = act ? n3 : bf[q].u[3];
                }
                Ecum += act ? (eb - 126) : 0;
            }
            {
                f32x4 acc[8];
                #pragma unroll
                for (int r = 0; r < 8; ++r) {
                    f32x4 z = {0.f, 0.f, 0.f, 0.f};
                    z = __builtin_amdgcn_mfma_f32_16x16x32_f16(afrag[r*4+0], bf[0].h, z, 0, 0, 0);
                    z = __builtin_amdgcn_mfma_f32_16x16x32_f16(afrag[r*4+1], bf[1].h, z, 0, 0, 0);
                    z = __builtin_amdgcn_mfma_f32_16x16x32_f16(afrag[r*4+2], bf[2].h, z, 0, 0, 0);
                    z = __builtin_amdgcn_mfma_f32_16x16x32_f16(afrag[r*4+3], bf[3].h, z, 0, 0, 0);
                    acc[r] = z;
                }
                const int tn = min(lo + k + 1, hi);
                const float* bp = em_c + (size_t)tn * Nq;
                #pragma unroll
                for (int r = 0; r < 8; ++r) {
                    const float2 x = *(const float2*)(bp + 16*r + 4*g);
                    const float2 y = *(const float2*)(bp + 16*r + 4*g + 2);
                    eeA[r].v = make_int2(pk16(__expf(x.x), __expf(x.y)),
                                         pk16(__expf(y.x), __expf(y.y)));
                }
                float w[32]; float mx = 0.f;
                #pragma unroll
                for (int r = 0; r < 8; ++r)
                    #pragma unroll
                    for (int i = 0; i < 4; ++i) {
                        const float ee = (float)eeB8[r].p[i >> 1][i & 1];
                        const float wv2 = acc[r][i] * ee;
                        w[r*4+i] = wv2; mx = fmaxf(mx, wv2);
                    }
                mx = fmaxf(mx, __shfl_xor(mx, 16, 64));
                mx = fmaxf(mx, __shfl_xor(mx, 32, 64));
                const int eb = (__float_as_int(mx) >> 23) & 255;
                const float sig = __int_as_float((253 - eb) << 23);
                const bool act = (k + 1 <= lenc);
                #pragma unroll
                for (int q = 0; q < 4; ++q) {
                    const int n0 = pk16(w[8*q+0]*sig, w[8*q+1]*sig);
                    const int n1 = pk16(w[8*q+2]*sig, w[8*q+3]*sig);
                    const int n2 = pk16(w[8*q+4]*sig, w[8*q+5]*sig);
                    const int n3 = pk16(w[8*q+6]*sig, w[8*q+7]*sig);
                    bf[q].u[0] = act ? n0 : bf[q].u[0];
                    bf[q].u[1] = act ? n1 : bf[q].u[1];
                    bf[q].u[2] = act ? n2 : bf[q].u[2];
                    bf[q].u[3] = act ? n3 : bf[q].u[3];
                }
                Ecum += act ? (eb - 126) : 0;
            }
        }
        if (k <= kmax) {
            f32x4 acc[8];
            #pragma unroll
            for (int r = 0; r < 8; ++r) {
                f32x4 z = {0.f, 0.f, 0.f, 0.f};
                z = __builtin_amdgcn_mfma_f32_16x16x32_f16(afrag[r*4+0], bf[0].h, z, 0, 0, 0);
                z = __builtin_amdgcn_mfma_f32_16x16x32_f16(afrag[r*4+1], bf[1].h, z, 0, 0, 0);
                z = __builtin_amdgcn_mfma_f32_16x16x32_f16(afrag[r*4+2], bf[2].h, z, 0, 0, 0);
                z = __builtin_amdgcn_mfma_f32_16x16x32_f16(afrag[r*4+3], bf[3].h, z, 0, 0, 0);
                acc[r] = z;
            }
            float w[32]; float mx = 0.f;
            #pragma unroll
            for (int r = 0; r < 8; ++r)
                #pragma unroll
                for (int i = 0; i < 4; ++i) {
                    const float ee = (float)eeA[r].p[i >> 1][i & 1];
                    const float wv2 = acc[r][i] * ee;
                    w[r*4+i] = wv2; mx = fmaxf(mx, wv2);
                }
            mx = fmaxf(mx, __shfl_xor(mx, 16, 64));
            mx = fmaxf(mx, __shfl_xor(mx, 32, 64));
            const int eb = (__float_as_int(mx) >> 23) & 255;
            const float sig = __int_as_float((253 - eb) << 23);
            const bool act = (k <= lenc);
            #pragma unroll
            for (int q = 0; q < 4; ++q) {
                const int n0 = pk16(w[8*q+0]*sig, w[8*q+1]*sig);
                const int n1 = pk16(w[8*q+2]*sig, w[8*q+3]*sig);
                const int n2 = pk16(w[8*q+4]*sig, w[8*q+5]*sig);
                const int n3 = pk16(w[8*q+6]*sig, w[8*q+7]*sig);
                bf[q].u[0] = act ? n0 : bf[q].u[0];
                bf[q].u[1] = act ? n1 : bf[q].u[1];
                bf[q].u[2] = act ? n2 : bf[q].u[2];
                bf[q].u[3] = act ? n3 : bf[q].u[3];
            }
            Ecum += act ? (eb - 126) : 0;
        }
    } else {
        E16 eeA[4], eeB8[4];
        {
            const float* bp = em_c + (size_t)hi * Nq;
            #pragma unroll
            for (int q = 0; q < 4; ++q) {
                const float2 x0 = *(const float2*)(bp + 32*q + 4*g);
                const float2 x1 = *(const float2*)(bp + 32*q + 4*g + 2);
                const float2 y0 = *(const float2*)(bp + 32*q + 16 + 4*g);
                const float2 y1 = *(const float2*)(bp + 32*q + 16 + 4*g + 2);
                eeA[q].v2[0] = make_int2(pk16(__expf(x0.x), __expf(x0.y)),
                                         pk16(__expf(x1.x), __expf(x1.y)));
                eeA[q].v2[1] = make_int2(pk16(__expf(y0.x), __expf(y0.y)),
                                         pk16(__expf(y1.x), __expf(y1.y)));
            }
        }
        for (; k <= kmax; ++k) {
            BU beff[4];
            #pragma unroll
            for (int q = 0; q < 4; ++q) beff[q].h = bf[q].h * eeA[q].h;
            f32x4 acc[8];
            #pragma unroll
            for (int r = 0; r < 8; ++r) {
                f32x4 z = {0.f, 0.f, 0.f, 0.f};
                z = __builtin_amdgcn_mfma_f32_16x16x32_f16(afrag[r*4+0], beff[0].h, z, 0, 0, 0);
                z = __builtin_amdgcn_mfma_f32_16x16x32_f16(afrag[r*4+1], beff[1].h, z, 0, 0, 0);
                z = __builtin_amdgcn_mfma_f32_16x16x32_f16(afrag[r*4+2], beff[2].h, z, 0, 0, 0);
                z = __builtin_amdgcn_mfma_f32_16x16x32_f16(afrag[r*4+3], beff[3].h, z, 0, 0, 0);
                acc[r] = z;
            }
            {
                const int tn = max(hi - k, lo);
                const float* bp = em_c + (size_t)tn * Nq;
                #pragma unroll
                for (int q = 0; q < 4; ++q) {
                    const float2 x0 = *(const float2*)(bp + 32*q + 4*g);
                    const float2 x1 = *(const float2*)(bp + 32*q + 4*g + 2);
                    const float2 y0 = *(const float2*)(bp + 32*q + 16 + 4*g);
                    const float2 y1 = *(const float2*)(bp + 32*q + 16 + 4*g + 2);
                    eeB8[q].v2[0] = make_int2(pk16(__expf(x0.x), __expf(x0.y)),
                                              pk16(__expf(x1.x), __expf(x1.y)));
                    eeB8[q].v2[1] = make_int2(pk16(__expf(y0.x), __expf(y0.y)),
                                              pk16(__expf(y1.x), __expf(y1.y)));
                }
            }
            float mx = 0.f;
            #pragma unroll
            for (int r = 0; r < 8; ++r)
                #pragma unroll
                for (int i = 0; i < 4; ++i) mx = fmaxf(mx, acc[r][i]);
            mx = fmaxf(mx, __shfl_xor(mx, 16, 64));
            mx = fmaxf(mx, __shfl_xor(mx, 32, 64));
            const int eb = (__float_as_int(mx) >> 23) & 255;
            const float sig = __int_as_float((253 - eb) << 23);
            const bool act = (k <= lenc);
            #pragma unroll
            for (int q = 0; q < 4; ++q) {
                const int n0 = pk16(acc[2*q][0]*sig,   acc[2*q][1]*sig);
                const int n1 = pk16(acc[2*q][2]*sig,   acc[2*q][3]*sig);
                const int n2 = pk16(acc[2*q+1][0]*sig, acc[2*q+1][1]*sig);
                const int n3 = pk16(acc[2*q+1][2]*sig, acc[2*q+1][3]*sig);
                bf[q].u[0] = act ? n0 : bf[q].u[0];
                bf[q].u[1] = act ? n1 : bf[q].u[1];
                bf[q].u[2] = act ? n2 : bf[q].u[2];
                bf[q].u[3] = act ? n3 : bf[q].u[3];
            }
            Ecum += act ? (eb - 126) : 0;
            #pragma unroll
            for (int q = 0; q < 4; ++q) { eeA[q].v2[0] = eeB8[q].v2[0]; eeA[q].v2[1] = eeB8[q].v2[1]; }
        }
    }

    // store vector (two contiguous float4 per call) + ledger
    {
        float* dst = isFwd ? (wsA + ((size_t)(s - 1) * Bq + b) * Nq)
                           : (wsB + ((size_t)(s - 2) * Bq + b) * Nq);
        #pragma unroll
        for (int q = 0; q < 4; ++q) {
            f32x4 v0, v1;
            #pragma unroll
            for (int t = 0; t < 4; ++t) { v0[t] = (float)bf[q].h[t]; v1[t] = (float)bf[q].h[4+t]; }
            *(f32x4*)(dst + 32*q + 4*g)      = v0;
            *(f32x4*)(dst + 32*q + 16 + 4*g) = v1;
        }
        if (g == 0) {
            const float led = M0c + (float)Ecum * LN2;
            if (isFwd) wsLa[(s - 1) * Bq + b] = led;
            else       wsLb[(s - 2) * Bq + b] = led;
        }
    }
}

// ---------------------------------------------------------------------------
// Combine (rank-1 telescope, proven R15-R20) + score finalize. 512 threads.
// ---------------------------------------------------------------------------
__global__ __launch_bounds__(512)
void crf_combine_kernel(const float* __restrict__ wsA,
                        const float* __restrict__ wsB,
                        const float* __restrict__ wsLa,
                        const float* __restrict__ wsLb,
                        const float* __restrict__ wsS,
                        float* __restrict__ out) {
    const int b = blockIdx.x;
    const int tid = threadIdx.x;
    const int wv = tid >> 6;
    const int l = tid & 63;
    __shared__ float part[8];

    float tot = 0.f;
    for (int s = 2 + wv; s <= SEG - 1; s += 8) {
        const float* bb = wsB + ((size_t)(s - 2) * Bq + b) * Nq;
        const float* aa = wsA + ((size_t)(s - 2) * Bq + b) * Nq;  // a_{s-1}
        float z = bb[l] * aa[l] + bb[l + 64] * aa[l + 64];
        float cc = bb[l] + bb[l + 64];
        #pragma unroll
        for (int off = 32; off >= 1; off >>= 1) {
            z += __shfl_xor(z, off, 64);
            cc += __shfl_xor(cc, off, 64);
        }
        tot += __logf(z) + wsLa[(s - 2) * Bq + b] - __logf(cc);
    }
    if (wv == 0) {
        const float* bb = wsB + ((size_t)(SEG - 2) * Bq + b) * Nq;
        const float* aa = wsA + ((size_t)(SEG - 2) * Bq + b) * Nq;
        float z = bb[l] * aa[l] + bb[l + 64] * aa[l + 64];
        #pragma unroll
        for (int off = 32; off >= 1; off >>= 1)
            z += __shfl_xor(z, off, 64);
        tot += __logf(z) + wsLb[(SEG - 2) * Bq + b] + wsLa[(SEG - 2) * Bq + b];
    }
    if (l == 0) part[wv] = tot;
    __syncthreads();
    if (tid == 0) {
        float tz = 0.f;
        #pragma unroll
        for (int i = 0; i < 8; ++i) tz += part[i];
        out[b] = tz;
        out[Bq + b] = (wsS[0 * Bq + b] + wsS[1 * Bq + b])
                    + (wsS[2 * Bq + b] + wsS[3 * Bq + b]);
    }
}

extern "C" void kernel_launch(void* const* d_in, const int* in_sizes, int n_in,
                              void* d_out, int out_size, void* d_ws, size_t ws_size,
                              hipStream_t stream) {
    const float* emissions   = (const float*)d_in[0];
    const int*   token_sizes = (const int*)d_in[1];
    const int*   targets     = (const int*)d_in[2];
    const float* transitions = (const float*)d_in[3];  // (1,1,128,128)
    const float* head        = (const float*)d_in[4];  // (1,1,128)
    const float* last        = (const float*)d_in[5];  // (1,1,128)
    float* out = (float*)d_out;                        // (2,64,1) flat

    char* wp = (char*)d_ws;
    int4* aF = (int4*)wp;                                wp += 32 * 64 * 16;              // 32 KB
    int4* aB = (int4*)wp;                                wp += 32 * 64 * 16;              // 32 KB
    float* wsA  = (float*)wp;                            wp += (size_t)NFW * Bq * Nq * 4; // 2 MB
    float* wsB  = (float*)wp;                            wp += (size_t)NBW * Bq * Nq * 4; // 2 MB
    float* wsLa = (float*)wp;                            wp += NFW * Bq * 4;
    float* wsLb = (float*)wp;                            wp += NBW * Bq * 4;
    float* wsS  = (float*)wp;

    crf_prep_kernel<<<16, 256, 0, stream>>>(transitions, aF, aB);
    crf_worker_kernel<<<Bq * WPC + 4 * Bq, 64, 0, stream>>>(
        emissions, aF, aB, token_sizes, targets, transitions, head, last,
        wsA, wsB, wsLa, wsLb, wsS);
    crf_combine_kernel<<<Bq, 512, 0, stream>>>(wsA, wsB, wsLa, wsLb, wsS, out);
}

// Round 22
// 43.370 us; speedup vs baseline: 1.2645x; 1.2645x over previous
//
#include <hip/hip_runtime.h>
#include <math.h>

#define Bq 64
#define Tq 1024
#define Nq 128
#define SEG 129              // segments per chain (R22: halved worker depth)
#define NFW (SEG - 1)        // 128 forward workers: s = 1..128
#define NBW (SEG - 1)        // 128 backward workers: s = 2..129
#define WPC 16               // worker waves per chain (8 fwd + 8 bwd)
#define LN2 0.6931471805599453f

typedef __attribute__((ext_vector_type(8))) _Float16 half8;
typedef __attribute__((ext_vector_type(2))) _Float16 h2;
typedef __attribute__((ext_vector_type(4))) float f32x4;

union BU { int u[4]; int4 v; half8 h; };
union E8 { int2 v; h2 p[2]; };          // 4 f16
union E16 { int2 v2[2]; half8 h; };     // 8 f16 as two int2 loads

__device__ __forceinline__ int pk16(float a, float b) {
    auto p = __builtin_amdgcn_cvt_pkrtz(a, b);
    return *(int*)&p;
}

// Permuted m-slot map (R20-proven): k-slot (call q, lane-group g, word j) holds
//   m = 16*(2q + (j>>2)) + 4g + (j&3)  == D-slot (same lane, acc[2q+(j>>2)], reg j&3)
__device__ __forceinline__ int MMAP(int q, int g, int j) {
    return 16 * (2 * q + (j >> 2)) + 4 * g + (j & 3);
}

// ---------------------------------------------------------------------------
// Prep: blocks 0..4095   : eeh = (f16) exp(emissions)   [16.8 MB]
//       blocks 4096..4111: pack exp(transitions) into PERMUTED fragment layout
//       blocks 4112..4175: gold-path score for chain (bid-4112) -> out[64+b]
// Score rides free inside the memory-bound eeh pass (no dependency).
// ---------------------------------------------------------------------------
__global__ __launch_bounds__(256)
void crf_prep_kernel(const float* __restrict__ em,
                     const float* __restrict__ trans,
                     const int* __restrict__ token_sizes,
                     const int* __restrict__ targets,
                     const float* __restrict__ head,
                     const float* __restrict__ last,
                     _Float16* __restrict__ eeh,
                     int4* __restrict__ aF, int4* __restrict__ aB,
                     float* __restrict__ out) {
    const int bid = blockIdx.x;
    const int tid = threadIdx.x;
    if (bid < 4096) {
        const size_t i = ((size_t)bid * 256 + tid) * 8;
        const float4* src = (const float4*)(em + i);
        float4 x0 = src[0], x1 = src[1];
        BU r;
        r.u[0] = pk16(__expf(x0.x), __expf(x0.y));
        r.u[1] = pk16(__expf(x0.z), __expf(x0.w));
        r.u[2] = pk16(__expf(x1.x), __expf(x1.y));
        r.u[3] = pk16(__expf(x1.z), __expf(x1.w));
        *(int4*)(eeh + i) = r.v;
        return;
    }
    if (bid < 4112) {
        const int fb = bid - 4096;            // 0..7 aF, 8..15 aB
        const bool fwd = (fb < 8);
        const int kf = (fb & 7) * 4 + (tid >> 6);   // fragment 0..31
        const int L = tid & 63;
        const int c = L & 15, g = L >> 4;
        const int r = kf >> 2, q = kf & 3;
        BU v;
        #pragma unroll
        for (int j = 0; j < 8; ++j) {
            const int m = MMAP(q, g, j);
            const int n = 16 * r + c;
            const float tv = fwd ? trans[m * Nq + n] : trans[n * Nq + m];
            v.h[j] = (_Float16)__expf(tv);
        }
        (fwd ? aF : aB)[kf * 64 + L] = v.v;
        return;
    }
    // ---------------- score path (one block per chain, 256 threads) --------
    {
        const int b = bid - 4112;
        const int tsz = token_sizes[b];
        const int* tg = targets + b * Tq;
        const float* emc = em + (size_t)b * Tq * Nq;
        float sc = 0.f;
        for (int t = tid; t < tsz; t += 256) {
            int cur = tg[t];
            sc += emc[(size_t)t * Nq + cur];
            if (t >= 1) sc += trans[tg[t - 1] * Nq + cur];
        }
        #pragma unroll
        for (int off = 32; off >= 1; off >>= 1)
            sc += __shfl_xor(sc, off, 64);
        __shared__ float wsum[4];
        if ((tid & 63) == 0) wsum[tid >> 6] = sc;
        __syncthreads();
        if (tid == 0) {
            float tot = (wsum[0] + wsum[1]) + (wsum[2] + wsum[3]);
            out[Bq + b] = tot + head[tg[0]] + last[tg[tsz - 1]];
        }
    }
}

// ---------------------------------------------------------------------------
// FWD step — R20-proven body (lane-local relayout, f16 ee from eeh).
// ---------------------------------------------------------------------------
__device__ __forceinline__ void fwd_step(
    int k, int lenc, int lo, int hi, int g,
    const _Float16* __restrict__ eeh_c,
    const half8 (&afrag)[32], BU (&bf)[4],
    E8 (&eeCur)[8], E8 (&eeNxt)[8], int& Ecum)
{
    f32x4 acc[8];
    #pragma unroll
    for (int r = 0; r < 8; ++r) {
        f32x4 z = {0.f, 0.f, 0.f, 0.f};
        z = __builtin_amdgcn_mfma_f32_16x16x32_f16(afrag[r*4+0], bf[0].h, z, 0, 0, 0);
        z = __builtin_amdgcn_mfma_f32_16x16x32_f16(afrag[r*4+1], bf[1].h, z, 0, 0, 0);
        z = __builtin_amdgcn_mfma_f32_16x16x32_f16(afrag[r*4+2], bf[2].h, z, 0, 0, 0);
        z = __builtin_amdgcn_mfma_f32_16x16x32_f16(afrag[r*4+3], bf[3].h, z, 0, 0, 0);
        acc[r] = z;
    }
    {   // prefetch next step's ee row (D layout: 8 x 8B per lane)
        const int tn = min(lo + k, hi);
        const _Float16* bp = eeh_c + (size_t)tn * Nq;
        #pragma unroll
        for (int r = 0; r < 8; ++r)
            eeNxt[r].v = *(const int2*)(bp + 16*r + 4*g);
    }
    float w[32];
    float mx = 0.f;
    #pragma unroll
    for (int r = 0; r < 8; ++r) {
        #pragma unroll
        for (int i = 0; i < 4; ++i) {
            const float ee = (float)eeCur[r].p[i >> 1][i & 1];
            const float wv = acc[r][i] * ee;
            w[r*4+i] = wv;
            mx = fmaxf(mx, wv);
        }
    }
    mx = fmaxf(mx, __shfl_xor(mx, 16, 64));
    mx = fmaxf(mx, __shfl_xor(mx, 32, 64));
    const int eb = (__float_as_int(mx) >> 23) & 255;
    const float sig = __int_as_float((253 - eb) << 23);
    const bool act = (k <= lenc);
    #pragma unroll
    for (int q = 0; q < 4; ++q) {   // D -> B: lane-local (permuted-E layout)
        const int n0 = pk16(w[8*q+0]*sig, w[8*q+1]*sig);
        const int n1 = pk16(w[8*q+2]*sig, w[8*q+3]*sig);
        const int n2 = pk16(w[8*q+4]*sig, w[8*q+5]*sig);
        const int n3 = pk16(w[8*q+6]*sig, w[8*q+7]*sig);
        bf[q].u[0] = act ? n0 : bf[q].u[0];
        bf[q].u[1] = act ? n1 : bf[q].u[1];
        bf[q].u[2] = act ? n2 : bf[q].u[2];
        bf[q].u[3] = act ? n3 : bf[q].u[3];
    }
    Ecum += act ? (eb - 126) : 0;
}

// ---------------------------------------------------------------------------
// BWD step — R20-proven body (ee pk_mul on B operand; lane-local relayout).
// ---------------------------------------------------------------------------
__device__ __forceinline__ void bwd_step(
    int k, int lenc, int lo, int hi, int g,
    const _Float16* __restrict__ eeh_c,
    const half8 (&afrag)[32], BU (&bf)[4],
    E16 (&eeCur)[4], E16 (&eeNxt)[4], int& Ecum)
{
    BU beff[4];
    #pragma unroll
    for (int q = 0; q < 4; ++q) beff[q].h = bf[q].h * eeCur[q].h;  // v_pk_mul_f16
    f32x4 acc[8];
    #pragma unroll
    for (int r = 0; r < 8; ++r) {
        f32x4 z = {0.f, 0.f, 0.f, 0.f};
        z = __builtin_amdgcn_mfma_f32_16x16x32_f16(afrag[r*4+0], beff[0].h, z, 0, 0, 0);
        z = __builtin_amdgcn_mfma_f32_16x16x32_f16(afrag[r*4+1], beff[1].h, z, 0, 0, 0);
        z = __builtin_amdgcn_mfma_f32_16x16x32_f16(afrag[r*4+2], beff[2].h, z, 0, 0, 0);
        z = __builtin_amdgcn_mfma_f32_16x16x32_f16(afrag[r*4+3], beff[3].h, z, 0, 0, 0);
        acc[r] = z;
    }
    {   // prefetch next step's ee row (permuted B layout: 2 int2 per q)
        const int tn = max(hi - k, lo);
        const _Float16* bp = eeh_c + (size_t)tn * Nq;
        #pragma unroll
        for (int q = 0; q < 4; ++q) {
            eeNxt[q].v2[0] = *(const int2*)(bp + 32*q + 4*g);
            eeNxt[q].v2[1] = *(const int2*)(bp + 32*q + 16 + 4*g);
        }
    }
    float mx = 0.f;
    #pragma unroll
    for (int r = 0; r < 8; ++r) {
        #pragma unroll
        for (int i = 0; i < 4; ++i) mx = fmaxf(mx, acc[r][i]);
    }
    mx = fmaxf(mx, __shfl_xor(mx, 16, 64));
    mx = fmaxf(mx, __shfl_xor(mx, 32, 64));
    const int eb = (__float_as_int(mx) >> 23) & 255;
    const float sig = __int_as_float((253 - eb) << 23);
    const bool act = (k <= lenc);
    #pragma unroll
    for (int q = 0; q < 4; ++q) {
        const int n0 = pk16(acc[2*q][0]*sig,   acc[2*q][1]*sig);
        const int n1 = pk16(acc[2*q][2]*sig,   acc[2*q][3]*sig);
        const int n2 = pk16(acc[2*q+1][0]*sig, acc[2*q+1][1]*sig);
        const int n3 = pk16(acc[2*q+1][2]*sig, acc[2*q+1][3]*sig);
        bf[q].u[0] = act ? n0 : bf[q].u[0];
        bf[q].u[1] = act ? n1 : bf[q].u[1];
        bf[q].u[2] = act ? n2 : bf[q].u[2];
        bf[q].u[3] = act ? n3 : bf[q].u[3];
    }
    Ecum += act ? (eb - 126) : 0;
}

// ---------------------------------------------------------------------------
// Worker waves only: bid: chain b=bid>>4, wv=bid&15 (0..7 fwd, 8..15 bwd).
// Column c of wave wv covers segment s = (fwd?1:2) + 16*(wv&7) + c.
// ---------------------------------------------------------------------------
__global__ __launch_bounds__(64, 1)
void crf_worker_kernel(const float* __restrict__ emissions,
                       const _Float16* __restrict__ eeh,
                       const int4* __restrict__ aF,
                       const int4* __restrict__ aB,
                       const int* __restrict__ token_sizes,
                       const float* __restrict__ head,
                       const float* __restrict__ last,
                       float* __restrict__ wsA, float* __restrict__ wsB,
                       float* __restrict__ wsLa, float* __restrict__ wsLb) {
    const int L = threadIdx.x;
    const int bid = blockIdx.x;

    const int b = bid >> 4;
    const int wv = bid & 15;
    const bool isFwd = (wv < 8);
    const int half_ = wv & 7;
    const int c = L & 15;
    const int g = L >> 4;
    const int s = (isFwd ? 1 : 2) + 16 * half_ + c;

    const float* em_c = emissions + (size_t)b * Tq * Nq;
    const _Float16* eeh_c = eeh + (size_t)b * Tq * Nq;
    const int tsz = token_sizes[b];
    const int nst = tsz - 1;
    const int base = nst / SEG;              // >= 3
    const int rem = nst % SEG;
    const int lo = 1 + (s - 1) * base + min(s - 1, rem);
    const int lenc = base + ((s <= rem) ? 1 : 0);
    const int hi = lo + lenc - 1;
    const int kmax = base + 1;

    // A fragments: 32 coalesced b128 loads (permuted layout from prep)
    half8 afrag[32];
    {
        const int4* asrc = isFwd ? aF : aB;
        #pragma unroll
        for (int kf = 0; kf < 32; ++kf) {
            BU t; t.v = asrc[kf * 64 + L];
            afrag[kf] = t.h;
        }
    }

    // init vector in PERMUTED B layout
    BU bf[4];
    float M0c;
    {
        float a0[32];
        float mx = -1e30f;
        #pragma unroll
        for (int q = 0; q < 4; ++q) {
            #pragma unroll
            for (int j2 = 0; j2 < 8; ++j2) {
                const int m = MMAP(q, g, j2);
                float v;
                if (isFwd) v = (s == 1)   ? (head[m] + em_c[m]) : 0.f;
                else       v = (s == SEG) ? last[m]             : 0.f;
                a0[q*8+j2] = v;
                mx = fmaxf(mx, v);
            }
        }
        mx = fmaxf(mx, __shfl_xor(mx, 16, 64));
        mx = fmaxf(mx, __shfl_xor(mx, 32, 64));
        M0c = mx;
        #pragma unroll
        for (int q = 0; q < 4; ++q) {
            #pragma unroll
            for (int p = 0; p < 4; ++p)
                bf[q].u[p] = pk16(__expf(a0[q*8+2*p]   - M0c),
                                  __expf(a0[q*8+2*p+1] - M0c));
        }
    }

    int Ecum = 0;
    int k = 1;
    if (isFwd) {
        E8 eeA[8], eeB8[8];
        const _Float16* bp = eeh_c + (size_t)lo * Nq;
        #pragma unroll
        for (int r = 0; r < 8; ++r) eeA[r].v = *(const int2*)(bp + 16*r + 4*g);
        for (; k + 1 <= kmax; k += 2) {
            fwd_step(k,   lenc, lo, hi, g, eeh_c, afrag, bf, eeA, eeB8, Ecum);
            fwd_step(k+1, lenc, lo, hi, g, eeh_c, afrag, bf, eeB8, eeA, Ecum);
        }
        if (k <= kmax)
            fwd_step(k, lenc, lo, hi, g, eeh_c, afrag, bf, eeA, eeB8, Ecum);
    } else {
        E16 eeA[4], eeB8[4];
        const _Float16* bp = eeh_c + (size_t)hi * Nq;
        #pragma unroll
        for (int q = 0; q < 4; ++q) {
            eeA[q].v2[0] = *(const int2*)(bp + 32*q + 4*g);
            eeA[q].v2[1] = *(const int2*)(bp + 32*q + 16 + 4*g);
        }
        for (; k + 1 <= kmax; k += 2) {
            bwd_step(k,   lenc, lo, hi, g, eeh_c, afrag, bf, eeA, eeB8, Ecum);
            bwd_step(k+1, lenc, lo, hi, g, eeh_c, afrag, bf, eeB8, eeA, Ecum);
        }
        if (k <= kmax)
            bwd_step(k, lenc, lo, hi, g, eeh_c, afrag, bf, eeA, eeB8, Ecum);
    }

    // store vector (two contiguous float4 per call) + ledger
    {
        float* dst = isFwd ? (wsA + ((size_t)(s - 1) * Bq + b) * Nq)
                           : (wsB + ((size_t)(s - 2) * Bq + b) * Nq);
        #pragma unroll
        for (int q = 0; q < 4; ++q) {
            f32x4 v0, v1;
            #pragma unroll
            for (int t = 0; t < 4; ++t) { v0[t] = (float)bf[q].h[t]; v1[t] = (float)bf[q].h[4+t]; }
            *(f32x4*)(dst + 32*q + 4*g)      = v0;
            *(f32x4*)(dst + 32*q + 16 + 4*g) = v1;
        }
        if (g == 0) {
            const float led = M0c + (float)Ecum * LN2;
            if (isFwd) wsLa[(s - 1) * Bq + b] = led;
            else       wsLb[(s - 2) * Bq + b] = led;
        }
    }
}

// ---------------------------------------------------------------------------
// Combine (rank-1 telescope, proven R15-R21): logZ only. 512 threads/chain.
// ---------------------------------------------------------------------------
__global__ __launch_bounds__(512)
void crf_combine_kernel(const float* __restrict__ wsA,
                        const float* __restrict__ wsB,
                        const float* __restrict__ wsLa,
                        const float* __restrict__ wsLb,
                        float* __restrict__ out) {
    const int b = blockIdx.x;
    const int tid = threadIdx.x;
    const int wv = tid >> 6;
    const int l = tid & 63;
    __shared__ float part[8];

    float tot = 0.f;
    for (int s = 2 + wv; s <= SEG - 1; s += 8) {
        const float* bb = wsB + ((size_t)(s - 2) * Bq + b) * Nq;
        const float* aa = wsA + ((size_t)(s - 2) * Bq + b) * Nq;  // a_{s-1}
        float z = bb[l] * aa[l] + bb[l + 64] * aa[l + 64];
        float cc = bb[l] + bb[l + 64];
        #pragma unroll
        for (int off = 32; off >= 1; off >>= 1) {
            z += __shfl_xor(z, off, 64);
            cc += __shfl_xor(cc, off, 64);
        }
        tot += __logf(z) + wsLa[(s - 2) * Bq + b] - __logf(cc);
    }
    if (wv == 0) {   // top junction: b_SEG . a_{SEG-1}
        const float* bb = wsB + ((size_t)(SEG - 2) * Bq + b) * Nq;
        const float* aa = wsA + ((size_t)(SEG - 2) * Bq + b) * Nq;
        float z = bb[l] * aa[l] + bb[l + 64] * aa[l + 64];
        #pragma unroll
        for (int off = 32; off >= 1; off >>= 1)
            z += __shfl_xor(z, off, 64);
        tot += __logf(z) + wsLb[(SEG - 2) * Bq + b] + wsLa[(SEG - 2) * Bq + b];
    }
    if (l == 0) part[wv] = tot;
    __syncthreads();
    if (tid == 0) {
        float tz = 0.f;
        #pragma unroll
        for (int i = 0; i < 8; ++i) tz += part[i];
        out[b] = tz;
    }
}

extern "C" void kernel_launch(void* const* d_in, const int* in_sizes, int n_in,
                              void* d_out, int out_size, void* d_ws, size_t ws_size,
                              hipStream_t stream) {
    const float* emissions   = (const float*)d_in[0];
    const int*   token_sizes = (const int*)d_in[1];
    const int*   targets     = (const int*)d_in[2];
    const float* transitions = (const float*)d_in[3];  // (1,1,128,128)
    const float* head        = (const float*)d_in[4];  // (1,1,128)
    const float* last        = (const float*)d_in[5];  // (1,1,128)
    float* out = (float*)d_out;                        // (2,64,1) flat

    char* wp = (char*)d_ws;
    _Float16* eeh = (_Float16*)wp;                       wp += (size_t)Bq * Tq * Nq * 2;  // 16.78 MB
    int4* aF = (int4*)wp;                                wp += 32 * 64 * 16;              // 32 KB
    int4* aB = (int4*)wp;                                wp += 32 * 64 * 16;              // 32 KB
    float* wsA  = (float*)wp;                            wp += (size_t)NFW * Bq * Nq * 4; // 4 MB
    float* wsB  = (float*)wp;                            wp += (size_t)NBW * Bq * Nq * 4; // 4 MB
    float* wsLa = (float*)wp;                            wp += NFW * Bq * 4;
    float* wsLb = (float*)wp;                            wp += NBW * Bq * 4;

    crf_prep_kernel<<<4096 + 16 + Bq, 256, 0, stream>>>(
        emissions, transitions, token_sizes, targets, head, last,
        eeh, aF, aB, out);
    crf_worker_kernel<<<Bq * WPC, 64, 0, stream>>>(
        emissions, eeh, aF, aB, token_sizes, head, last,
        wsA, wsB, wsLa, wsLb);
    crf_combine_kernel<<<Bq, 512, 0, stream>>>(wsA, wsB, wsLa, wsLb, out);
}